// Round 3
// baseline (142.079 us; speedup 1.0000x reference)
//
#include <hip/hip_runtime.h>

// ABELSpline: B=1024, D=128, DENSITY=259, ODIM=64, IDIM=512
// out[b,o] = direct[b,o] + sum_n c_n*(exp(z[b,o*8+n]) - exp(z[b,o*8+4+n])), c_n=(n+1)^-2
// direct[b,o] = sum_{d,k} w[b,d,k] * dtab[d*259 + p[b,d] + k, o]
// z[b,j]      = sum_{d,k} w[b,d,k] * itab[d*259 + p[b,d] + k, j]
// p = floor(256*x), w = cubic B-spline basis of frac(256*x); p+3 <= 258 so no mod wrap.
//
// Round 2: column-parallel within a block. 512 threads = 8 waves; thread j owns
// indirect col j (register accumulator); wave 0 lanes also own the 64 direct cols.
// ALL threads process the same dim at the same time -> single ~600KB table region
// hot in L2 chip-wide (round-1's dim-split quadrupled L2-miss traffic: 257->470MB).

constexpr int BATCH = 1024;
constexpr int DIN = 128;
constexpr int DENSITY = 259;
constexpr int ODIM = 64;
constexpr int IDIM = 512;
constexpr int TPB = 512;

__global__ __launch_bounds__(TPB) void abel_spline_kernel(
    const float* __restrict__ x,
    const float* __restrict__ dtab,
    const float* __restrict__ itab,
    float* __restrict__ out)
{
    __shared__ float4 s_w[DIN];     // spline weights per dim
    __shared__ int    s_base[DIN];  // d*259 + floor(256*x_d)
    __shared__ float  s_z[IDIM];
    __shared__ float  s_dir[ODIM];

    const int b   = blockIdx.x;
    const int tid = threadIdx.x;

    // ---- phase 1: per-dim spline weights + base row index
    if (tid < DIN) {
        float xv = x[b * DIN + tid];
        float t  = xv * 256.0f;             // scale = DENSITY-3 = 256
        float fl = floorf(t);
        float f  = t - fl;
        float f2 = f * f;
        float f3 = f2 * f;
        float om = 1.0f - f;
        float w0 = om * om * om * (1.0f / 6.0f);
        float w1 = (3.0f * f3 - 6.0f * f2 + 4.0f) * (1.0f / 6.0f);
        float w2 = (-3.0f * f3 + 3.0f * f2 + 3.0f * f + 1.0f) * (1.0f / 6.0f);
        float w3 = f3 * (1.0f / 6.0f);
        s_w[tid]    = make_float4(w0, w1, w2, w3);
        s_base[tid] = tid * DENSITY + (int)fl;
    }
    __syncthreads();

    float accI = 0.0f;                      // indirect col `tid`
    float accD = 0.0f;                      // direct col `tid` (tid < 64)
    const bool doD = (tid < ODIM);          // wave 0 only, all 64 lanes active

    const float* __restrict__ itc = itab + tid;   // column pointer, row stride IDIM
    const float* __restrict__ dtc = dtab + tid;   // column pointer, row stride ODIM

    // ---- phase 2: all threads walk dims together; unroll 2 for load ILP
    #pragma unroll 2
    for (int d = 0; d < DIN; d += 2) {
        const int    b0 = s_base[d];
        const int    b1 = s_base[d + 1];
        const float4 w0 = s_w[d];
        const float4 w1 = s_w[d + 1];

        const float* r0 = itc + (size_t)b0 * IDIM;
        const float* r1 = itc + (size_t)b1 * IDIM;
        float v00 = r0[0 * IDIM], v01 = r0[1 * IDIM], v02 = r0[2 * IDIM], v03 = r0[3 * IDIM];
        float v10 = r1[0 * IDIM], v11 = r1[1 * IDIM], v12 = r1[2 * IDIM], v13 = r1[3 * IDIM];

        if (doD) {
            const float* q0 = dtc + (size_t)b0 * ODIM;
            const float* q1 = dtc + (size_t)b1 * ODIM;
            float u00 = q0[0 * ODIM], u01 = q0[1 * ODIM], u02 = q0[2 * ODIM], u03 = q0[3 * ODIM];
            float u10 = q1[0 * ODIM], u11 = q1[1 * ODIM], u12 = q1[2 * ODIM], u13 = q1[3 * ODIM];
            accD = fmaf(w0.x, u00, accD);
            accD = fmaf(w0.y, u01, accD);
            accD = fmaf(w0.z, u02, accD);
            accD = fmaf(w0.w, u03, accD);
            accD = fmaf(w1.x, u10, accD);
            accD = fmaf(w1.y, u11, accD);
            accD = fmaf(w1.z, u12, accD);
            accD = fmaf(w1.w, u13, accD);
        }

        accI = fmaf(w0.x, v00, accI);
        accI = fmaf(w0.y, v01, accI);
        accI = fmaf(w0.z, v02, accI);
        accI = fmaf(w0.w, v03, accI);
        accI = fmaf(w1.x, v10, accI);
        accI = fmaf(w1.y, v11, accI);
        accI = fmaf(w1.z, v12, accI);
        accI = fmaf(w1.w, v13, accI);
    }

    s_z[tid] = accI;
    if (doD) s_dir[tid] = accD;
    __syncthreads();

    // ---- phase 3: anti-symmetric exponential combine (64 outputs)
    if (tid < ODIM) {
        const float* zp = s_z + tid * 8;
        float pos = __expf(zp[0]) + 0.25f * __expf(zp[1])
                  + (1.0f / 9.0f) * __expf(zp[2]) + 0.0625f * __expf(zp[3]);
        float neg = __expf(zp[4]) + 0.25f * __expf(zp[5])
                  + (1.0f / 9.0f) * __expf(zp[6]) + 0.0625f * __expf(zp[7]);
        out[b * ODIM + tid] = s_dir[tid] + pos - neg;
    }
}

extern "C" void kernel_launch(void* const* d_in, const int* in_sizes, int n_in,
                              void* d_out, int out_size, void* d_ws, size_t ws_size,
                              hipStream_t stream) {
    const float* x    = (const float*)d_in[0];
    const float* dtab = (const float*)d_in[1];
    const float* itab = (const float*)d_in[2];
    float* out = (float*)d_out;
    hipLaunchKernelGGL(abel_spline_kernel, dim3(BATCH), dim3(TPB), 0, stream,
                       x, dtab, itab, out);
}

// Round 4
// 62.781 us; speedup vs baseline: 2.2631x; 2.2631x over previous
//
#include <hip/hip_runtime.h>

// ABELSpline: B=1024, D=128, DENSITY=259, ODIM=64, IDIM=512
// out[b,o] = direct[b,o] + sum_n c_n*(exp(z[b,8o+n]) - exp(z[b,8o+4+n])), c_n=(n+1)^-2
// direct[b,o] = sum_{d,k} w[b,d,k] * dtab[d*259 + p[b,d] + k, o]
// z[b,j]      = sum_{d,k} w[b,d,k] * itab[d*259 + p[b,d] + k, j]
// p = floor(256*x); p+3 <= 258 so the reference's mod never wraps.
//
// Round 3: COLUMN-SLICED across XCDs. Rounds 1-2 were L2-fill-BW bound at the
// structural floor (each XCD's batch rows touch ~86% of the 76MB tables ->
// ~473MB aggregate L2 fetch @ 3.45TB/s = 139us). The epilogue is column-local
// (output o uses indirect cols 8o..8o+7, direct col o), so slice columns into
// 8 groups of 8 outputs, pin slice s to XCD s (blockIdx%8 round-robin). Each
// XCD then fetches only its 64-col stripe (~8.5MB + ~3.6MB direct) for ALL
// batch rows -> ~100MB aggregate.

constexpr int BATCH = 1024;
constexpr int DIN = 128;
constexpr int DENSITY = 259;
constexpr int ODIM = 64;
constexpr int IDIM = 512;
constexpr int SLICES = 8;           // = #XCDs; 8 outputs / 64 indirect cols each
constexpr int RPB = 8;              // batch rows per block
constexpr int TPB = 256;            // 4 waves; wave w handles batch rows 2w,2w+1

__device__ __forceinline__ void fma4(float4& a, float s, const float4 v) {
    a.x = fmaf(s, v.x, a.x);
    a.y = fmaf(s, v.y, a.y);
    a.z = fmaf(s, v.z, a.z);
    a.w = fmaf(s, v.w, a.w);
}

__device__ __forceinline__ float4 shfl_xor4(float4 v, int m) {
    return make_float4(__shfl_xor(v.x, m), __shfl_xor(v.y, m),
                       __shfl_xor(v.z, m), __shfl_xor(v.w, m));
}

__global__ __launch_bounds__(TPB) void abel_spline_kernel(
    const float* __restrict__ x,
    const float* __restrict__ dtab,
    const float* __restrict__ itab,
    float* __restrict__ out)
{
    __shared__ float4 s_w[RPB][DIN];     // spline weights per (row, dim)
    __shared__ int    s_base[RPB][DIN];  // d*259 + floor(256*x)
    __shared__ float  s_z[RPB][64];      // z for this slice's 64 indirect cols
    __shared__ float4 s_dirp[4][16];     // per-wave direct partials: [wave][r*2+j]

    const int bid   = blockIdx.x;
    const int slice = bid & (SLICES - 1);   // round-robin -> XCD-pinned stripe
    const int chunk = bid >> 3;             // 0..127
    const int tid   = threadIdx.x;
    const int wv    = tid >> 6;
    const int lane  = tid & 63;
    const int rowbase = chunk * RPB;

    // ---- phase 1: weights + base row index for all (r,d) pairs
    for (int i = tid; i < RPB * DIN; i += TPB) {
        const int r = i >> 7;       // 0..7
        const int d = i & 127;
        float xv = x[(rowbase + r) * DIN + d];
        float t  = xv * 256.0f;     // scale = DENSITY-3 = 256
        float fl = floorf(t);
        float f  = t - fl;
        float f2 = f * f;
        float f3 = f2 * f;
        float om = 1.0f - f;
        float w0 = om * om * om * (1.0f / 6.0f);
        float w1 = (3.0f * f3 - 6.0f * f2 + 4.0f) * (1.0f / 6.0f);
        float w2 = (-3.0f * f3 + 3.0f * f2 + 3.0f * f + 1.0f) * (1.0f / 6.0f);
        float w3 = f3 * (1.0f / 6.0f);
        s_w[r][d]    = make_float4(w0, w1, w2, w3);
        s_base[r][d] = d * DENSITY + (int)fl;
    }
    __syncthreads();

    // ---- phase 2a: indirect stripe. lane = knot q (lane>>4) x col-quad c4 (lane&15).
    // One wave-load covers a full (row,dim) window: 4 knots x 16 float4 = 1KB.
    const int q  = lane >> 4;
    const int c4 = lane & 15;
    const float* __restrict__ itL = itab + (size_t)q * IDIM + slice * 64 + c4 * 4;
    const int r0 = 2 * wv, r1 = 2 * wv + 1;

    float4 a0 = make_float4(0.f, 0.f, 0.f, 0.f);
    float4 a1 = make_float4(0.f, 0.f, 0.f, 0.f);

    #pragma unroll 2
    for (int d = 0; d < DIN; ++d) {
        const int   b0 = s_base[r0][d];
        const int   b1 = s_base[r1][d];
        const float w0 = ((const float*)&s_w[r0][d])[q];
        const float w1 = ((const float*)&s_w[r1][d])[q];
        float4 v0 = *(const float4*)(itL + (size_t)b0 * IDIM);
        float4 v1 = *(const float4*)(itL + (size_t)b1 * IDIM);
        fma4(a0, w0, v0);
        fma4(a1, w1, v1);
    }

    // ---- phase 2b: direct stripe (8 cols). lane = r(3b) | q(2b) | j(1b);
    // each wave covers dims d ≡ wv (mod 4).
    const int rD = lane >> 3;
    const int qD = (lane >> 1) & 3;
    const int jD = lane & 1;
    const float* __restrict__ dtL = dtab + (size_t)qD * ODIM + slice * 8 + jD * 4;
    float4 aD = make_float4(0.f, 0.f, 0.f, 0.f);
    for (int d = wv; d < DIN; d += 4) {
        const int   bD = s_base[rD][d];
        const float wD = ((const float*)&s_w[rD][d])[qD];
        float4 u = *(const float4*)(dtL + (size_t)bD * ODIM);
        fma4(aD, wD, u);
    }
    // reduce over knot qD (lane bits 1-2)
    {
        float4 t = shfl_xor4(aD, 2); aD.x += t.x; aD.y += t.y; aD.z += t.z; aD.w += t.w;
        t = shfl_xor4(aD, 4);        aD.x += t.x; aD.y += t.y; aD.z += t.z; aD.w += t.w;
        if (qD == 0) s_dirp[wv][rD * 2 + jD] = aD;
    }

    // reduce indirect over knot q (lane bits 4-5)
    {
        float4 t = shfl_xor4(a0, 16); a0.x += t.x; a0.y += t.y; a0.z += t.z; a0.w += t.w;
        t = shfl_xor4(a0, 32);        a0.x += t.x; a0.y += t.y; a0.z += t.z; a0.w += t.w;
        t = shfl_xor4(a1, 16);        a1.x += t.x; a1.y += t.y; a1.z += t.z; a1.w += t.w;
        t = shfl_xor4(a1, 32);        a1.x += t.x; a1.y += t.y; a1.z += t.z; a1.w += t.w;
        if (q == 0) {
            reinterpret_cast<float4*>(s_z[r0])[c4] = a0;
            reinterpret_cast<float4*>(s_z[r1])[c4] = a1;
        }
    }
    __syncthreads();

    // ---- phase 3: epilogue, 64 threads = 8 rows x 8 outputs of this slice
    if (tid < RPB * 8) {
        const int r  = tid >> 3;
        const int oo = tid & 7;
        const int j  = oo >> 2;
        const int cc = oo & 3;
        float dir = ((const float*)&s_dirp[0][r * 2 + j])[cc]
                  + ((const float*)&s_dirp[1][r * 2 + j])[cc]
                  + ((const float*)&s_dirp[2][r * 2 + j])[cc]
                  + ((const float*)&s_dirp[3][r * 2 + j])[cc];
        const float* zp = s_z[r] + oo * 8;
        float pos = __expf(zp[0]) + 0.25f * __expf(zp[1])
                  + (1.0f / 9.0f) * __expf(zp[2]) + 0.0625f * __expf(zp[3]);
        float neg = __expf(zp[4]) + 0.25f * __expf(zp[5])
                  + (1.0f / 9.0f) * __expf(zp[6]) + 0.0625f * __expf(zp[7]);
        out[(rowbase + r) * ODIM + slice * 8 + oo] = dir + pos - neg;
    }
}

extern "C" void kernel_launch(void* const* d_in, const int* in_sizes, int n_in,
                              void* d_out, int out_size, void* d_ws, size_t ws_size,
                              hipStream_t stream) {
    const float* x    = (const float*)d_in[0];
    const float* dtab = (const float*)d_in[1];
    const float* itab = (const float*)d_in[2];
    float* out = (float*)d_out;
    hipLaunchKernelGGL(abel_spline_kernel, dim3(BATCH / RPB * SLICES), dim3(TPB), 0, stream,
                       x, dtab, itab, out);
}